// Round 7
// baseline (176.679 us; speedup 1.0000x reference)
//
#include <hip/hip_runtime.h>

#define DD 128

typedef short bf16x8 __attribute__((ext_vector_type(8)));
typedef float f32x4 __attribute__((ext_vector_type(4)));

__device__ __forceinline__ unsigned short f2bf(float f) {   // fp32 -> bf16, RNE
    unsigned int u = __builtin_bit_cast(unsigned int, f);
    u += 0x7fffu + ((u >> 16) & 1u);
    return (unsigned short)(u >> 16);
}
__device__ __forceinline__ float bflo(unsigned int u) { return __builtin_bit_cast(float, u << 16); }
__device__ __forceinline__ float bfhi(unsigned int u) { return __builtin_bit_cast(float, u & 0xffff0000u); }

// ---------------- edge count ----------------
__global__ __launch_bounds__(512) void k_count(const int* __restrict__ col,
                                               int* __restrict__ cnt, int E) {
    int e = blockIdx.x * 512 + threadIdx.x;
    if (e < E) atomicAdd(&cnt[col[e]], 1);
}

// ---------------- scan phases ----------------
__global__ __launch_bounds__(256) void k_part(const int* __restrict__ cnt,
                                              int* __restrict__ part, int n) {
    __shared__ int s[256];
    int t = threadIdx.x;
    int i = blockIdx.x * 256 + t;
    s[t] = (i < n) ? cnt[i] : 0;
    __syncthreads();
    for (int off = 128; off > 0; off >>= 1) {
        if (t < off) s[t] += s[t + off];
        __syncthreads();
    }
    if (t == 0) part[blockIdx.x] = s[0];
}

__global__ __launch_bounds__(1024) void k_scanpart(int* __restrict__ part, int nblk) {
    __shared__ int s[1024];
    int t = threadIdx.x;
    int v = (t < nblk) ? part[t] : 0;
    s[t] = v;
    __syncthreads();
    for (int off = 1; off < 1024; off <<= 1) {
        int u = (t >= off) ? s[t - off] : 0;
        __syncthreads();
        s[t] += u;
        __syncthreads();
    }
    if (t < nblk) part[t] = s[t] - v;   // exclusive
}

__global__ __launch_bounds__(256) void k_apply(const int* __restrict__ cnt,
                                               const int* __restrict__ part,
                                               int* __restrict__ rowptr,
                                               int* __restrict__ cursor,
                                               float* __restrict__ dis, int n) {
    __shared__ int s[256];
    int t = threadIdx.x;
    int i = blockIdx.x * 256 + t;
    int c = (i < n) ? cnt[i] : 0;
    s[t] = c;
    __syncthreads();
    for (int off = 1; off < 256; off <<= 1) {
        int u = (t >= off) ? s[t - off] : 0;
        __syncthreads();
        s[t] += u;
        __syncthreads();
    }
    int base = part[blockIdx.x] + s[t] - c;
    if (i < n) {
        rowptr[i] = base;
        cursor[i] = base;
        dis[i] = rsqrtf((float)c + 1.0f);
        if (i == n - 1) rowptr[n] = base + c;
    }
}

// ---------------- MFMA GEMM: Y(bf16) = X @ W^T  (+ optional fused permute) ----------------
// 512 threads = 8 waves, 128 rows/block. Operand-swapped MFMA.
// Epilogue bounces acc through LDS (16B-granule XOR swizzle) so every global store
// instruction covers contiguous full 64B lines (write-allocate fix).
template <bool INBF16, bool FUSE_PERM>
__global__ __launch_bounds__(512) void k_gemm_mfma(const void* __restrict__ Xv,
                                                   const float* __restrict__ W,
                                                   unsigned short* __restrict__ Y,
                                                   int nrows, int gemm_blocks,
                                                   const int* __restrict__ erow,
                                                   const int* __restrict__ ecol,
                                                   int* __restrict__ cursor,
                                                   int* __restrict__ srow, int E) {
    __shared__ unsigned short Ws[128 * 128];   // 32 KB
    const int t = threadIdx.x;

    if (FUSE_PERM && blockIdx.x >= gemm_blocks) {
        int e = (blockIdx.x - gemm_blocks) * 512 + t;
        if (e < E) {
            int p = atomicAdd(&cursor[ecol[e]], 1);
            srow[p] = erow[e];
        }
        return;
    }

    // stage W: fp32 -> bf16, 16B-chunk XOR swizzle. 2048 chunks / 512 thr = 4 each
    #pragma unroll
    for (int i = 0; i < 4; ++i) {
        int g  = i * 512 + t;
        int wr = g >> 4, ch = g & 15;
        const float* src = W + wr * 128 + ch * 8;
        float4 f0 = *(const float4*)src;
        float4 f1 = *(const float4*)(src + 4);
        unsigned short u[8] = { f2bf(f0.x), f2bf(f0.y), f2bf(f0.z), f2bf(f0.w),
                                f2bf(f1.x), f2bf(f1.y), f2bf(f1.z), f2bf(f1.w) };
        int dst = wr * 128 + ((ch ^ (wr & 15)) << 3);
        *(uint4*)&Ws[dst] = *(const uint4*)u;
    }
    __syncthreads();

    const int wid  = t >> 6;          // 0..7
    const int lane = t & 63;
    const int lr   = lane & 15;
    const int lk   = lane >> 4;
    const int wrow = wid * 16 + lr;   // 0..127 (block-local output row)
    const long base = (long)blockIdx.x * 128;

    long arow = base + wrow;
    if (arow >= nrows) arow = nrows - 1;   // clamp loads; stores guarded later

    f32x4 acc[8] = {};

    #pragma unroll
    for (int kc = 0; kc < 4; ++kc) {
        bf16x8 af;
        if (INBF16) {
            const unsigned short* ap = (const unsigned short*)Xv + arow * 128 + kc * 32 + lk * 8;
            af = *(const bf16x8*)ap;
        } else {
            const float* ap = (const float*)Xv + arow * 128 + kc * 32 + lk * 8;
            float4 a0 = *(const float4*)ap;
            float4 a1 = *(const float4*)(ap + 4);
            af[0] = (short)f2bf(a0.x); af[1] = (short)f2bf(a0.y);
            af[2] = (short)f2bf(a0.z); af[3] = (short)f2bf(a0.w);
            af[4] = (short)f2bf(a1.x); af[5] = (short)f2bf(a1.y);
            af[6] = (short)f2bf(a1.z); af[7] = (short)f2bf(a1.w);
        }
        #pragma unroll
        for (int jt = 0; jt < 8; ++jt) {
            int j  = jt * 16 + lr;
            int ch = (kc * 4 + lk) ^ lr;
            const bf16x8* bp = (const bf16x8*)&Ws[j * 128 + (ch << 3)];
            acc[jt] = __builtin_amdgcn_mfma_f32_16x16x32_bf16(*bp, af, acc[jt], 0, 0, 0);
        }
    }

    // ---- epilogue: acc -> LDS (swizzled) -> full-line global stores ----
    __syncthreads();   // all Ws reads done before overwrite
    // lane holds row wrow, cols jt*16 + lk*4 + r  => 8B chunk cc = jt*4+lk
    #pragma unroll
    for (int jt = 0; jt < 8; ++jt) {
        unsigned int d0 = (unsigned int)f2bf(acc[jt][0]) | ((unsigned int)f2bf(acc[jt][1]) << 16);
        unsigned int d1 = (unsigned int)f2bf(acc[jt][2]) | ((unsigned int)f2bf(acc[jt][3]) << 16);
        int cc16 = jt * 2 + (lk >> 1);          // 16B-granule index 0..15
        int half = lk & 1;                      // which 8B half
        uint2 u; u.x = d0; u.y = d1;
        *(uint2*)&Ws[wrow * 128 + ((cc16 ^ lr) << 3) + half * 4] = u;
    }
    __syncthreads();
    // read out: 4 passes, each instruction stores 1KB contiguous per wave
    #pragma unroll
    for (int p = 0; p < 4; ++p) {
        int r    = p * 32 + (t >> 4);           // block-local row 0..127
        int cc16 = t & 15;
        long grow = base + r;
        if (grow < nrows) {
            uint4 v = *(const uint4*)&Ws[r * 128 + ((cc16 ^ (r & 15)) << 3)];
            *(uint4*)(Y + grow * 128 + cc16 * 8) = v;
        }
    }
}

// ---------------- gather-aggregate + self-loop + bias + relu ----------------
__device__ __forceinline__ void fma8(float* acc, float nm, uint4 q) {
    acc[0] += nm * bflo(q.x); acc[1] += nm * bfhi(q.x);
    acc[2] += nm * bflo(q.y); acc[3] += nm * bfhi(q.y);
    acc[4] += nm * bflo(q.z); acc[5] += nm * bfhi(q.z);
    acc[6] += nm * bflo(q.w); acc[7] += nm * bfhi(q.w);
}

template <bool OUTBF16>
__global__ __launch_bounds__(256) void k_agg(const int* __restrict__ rowptr,
                                             const int* __restrict__ srow,
                                             const float* __restrict__ dis,
                                             const unsigned short* __restrict__ xw,
                                             const float* __restrict__ b,
                                             void* __restrict__ outv, int n) {
    int v = blockIdx.x * 16 + (threadIdx.x >> 4);
    if (v >= n) return;
    int c = (threadIdx.x & 15) * 8;

    float dv = dis[v], s = dv * dv;
    float acc[8] = {};
    fma8(acc, s, *(const uint4*)(xw + (long)v * 128 + c));   // self-loop term

    int e0 = rowptr[v], e1 = rowptr[v + 1];
    int e = e0;
    for (; e + 4 <= e1; e += 4) {
        int   r1 = srow[e],     r2 = srow[e + 1];
        int   r3 = srow[e + 2], r4 = srow[e + 3];
        float n1 = dis[r1] * dv, n2 = dis[r2] * dv;
        float n3 = dis[r3] * dv, n4 = dis[r4] * dv;
        uint4 q1 = *(const uint4*)(xw + (long)r1 * 128 + c);
        uint4 q2 = *(const uint4*)(xw + (long)r2 * 128 + c);
        uint4 q3 = *(const uint4*)(xw + (long)r3 * 128 + c);
        uint4 q4 = *(const uint4*)(xw + (long)r4 * 128 + c);
        fma8(acc, n1, q1);
        fma8(acc, n2, q2);
        fma8(acc, n3, q3);
        fma8(acc, n4, q4);
    }
    for (; e < e1; ++e) {
        int   r1 = srow[e];
        float n1 = dis[r1] * dv;
        fma8(acc, n1, *(const uint4*)(xw + (long)r1 * 128 + c));
    }

    float4 b0 = *(const float4*)(b + c);
    float4 b1 = *(const float4*)(b + c + 4);
    float o[8];
    o[0] = fmaxf(acc[0] + b0.x, 0.0f); o[1] = fmaxf(acc[1] + b0.y, 0.0f);
    o[2] = fmaxf(acc[2] + b0.z, 0.0f); o[3] = fmaxf(acc[3] + b0.w, 0.0f);
    o[4] = fmaxf(acc[4] + b1.x, 0.0f); o[5] = fmaxf(acc[5] + b1.y, 0.0f);
    o[6] = fmaxf(acc[6] + b1.z, 0.0f); o[7] = fmaxf(acc[7] + b1.w, 0.0f);

    if (OUTBF16) {
        unsigned int pk[4];
        pk[0] = (unsigned int)f2bf(o[0]) | ((unsigned int)f2bf(o[1]) << 16);
        pk[1] = (unsigned int)f2bf(o[2]) | ((unsigned int)f2bf(o[3]) << 16);
        pk[2] = (unsigned int)f2bf(o[4]) | ((unsigned int)f2bf(o[5]) << 16);
        pk[3] = (unsigned int)f2bf(o[6]) | ((unsigned int)f2bf(o[7]) << 16);
        *(uint4*)((unsigned short*)outv + (long)v * 128 + c) = *(const uint4*)pk;
    } else {
        float* op = (float*)outv + (long)v * 128 + c;
        *(float4*)op       = make_float4(o[0], o[1], o[2], o[3]);
        *(float4*)(op + 4) = make_float4(o[4], o[5], o[6], o[7]);
    }
}

extern "C" void kernel_launch(void* const* d_in, const int* in_sizes, int n_in,
                              void* d_out, int out_size, void* d_ws, size_t ws_size,
                              hipStream_t stream) {
    const float* X  = (const float*)d_in[0];
    const float* W1 = (const float*)d_in[1];
    const float* b1 = (const float*)d_in[2];
    const float* W2 = (const float*)d_in[3];
    const float* b2 = (const float*)d_in[4];
    const int*   ei = (const int*)d_in[5];
    const int N = in_sizes[0] / DD;          // 100000
    const int E = in_sizes[5] / 2;           // 640000
    const int* row = ei;
    const int* col = ei + E;

    // -------- workspace carve-up --------
    char* p = (char*)d_ws;
    auto carve = [&](size_t bytes) { char* q = p; p += (bytes + 255) & ~(size_t)255; return q; };
    int*            cnt    = (int*)           carve((size_t)N * 4);
    int*            rowptr = (int*)           carve((size_t)(N + 1) * 4);
    int*            cursor = (int*)           carve((size_t)N * 4);
    int*            part   = (int*)           carve(1024 * 4);
    int*            srow   = (int*)           carve((size_t)E * 4);
    float*          dis    = (float*)         carve((size_t)N * 4);
    unsigned short* xw     = (unsigned short*)carve((size_t)N * DD * 2);   // bf16
    unsigned short* h1     = (unsigned short*)d_out;                       // bf16 scratch in d_out

    const int NBLK = (N + 255) / 256;              // scan blocks
    const int gemm_grid  = (N + 127) / 128;        // 782 (512-thread blocks)
    const int edge_grid  = (E + 511) / 512;        // 1250
    const int agg_grid   = (N + 15) / 16;

    // -------- CSR build prefix (count early; permute fused into GEMM1) --------
    hipMemsetAsync(cnt, 0, (size_t)N * 4, stream);
    k_count<<<edge_grid, 512, 0, stream>>>(col, cnt, E);
    k_part<<<NBLK, 256, 0, stream>>>(cnt, part, N);
    k_scanpart<<<1, 1024, 0, stream>>>(part, NBLK);
    k_apply<<<NBLK, 256, 0, stream>>>(cnt, part, rowptr, cursor, dis, N);

    // -------- fused: GEMM1 (X fp32 -> xw bf16) + edge permute --------
    k_gemm_mfma<false, true><<<gemm_grid + edge_grid, 512, 0, stream>>>(
        X, W1, xw, N, gemm_grid, row, col, cursor, srow, E);

    // ---- layer 1 aggregate ----
    k_agg<true><<<agg_grid, 256, 0, stream>>>(rowptr, srow, dis, xw, b1, h1, N);

    // ---- layer 2 ----  (h1 bf16 lives in d_out; GEMM2 consumes it before AGG2 overwrites)
    k_gemm_mfma<true, false><<<gemm_grid, 512, 0, stream>>>(
        h1, W2, xw, N, gemm_grid, nullptr, nullptr, nullptr, nullptr, 0);
    k_agg<false><<<agg_grid, 256, 0, stream>>>(rowptr, srow, dis, xw, b2, d_out, N);
}